// Round 7
// baseline (314.445 us; speedup 1.0000x reference)
//
#include <hip/hip_runtime.h>
#include <hip/hip_bf16.h>

// Problem constants
#define B_  128
#define T_  512
#define D_  400
#define NV  1024
#define NA  128

#define TILE_BYTES 13312          // 13 kk-blocks x 1024 B per 16-t tile
#define MAIN_BLOCKS 512           // 128 b x 4 v-chunks of 256

// Fallback (no-workspace) tiling
#define LDH  424
#define NT   32
#define FB_MAIN_BLOCKS 1024

typedef __bf16 bf16_t;
typedef bf16_t bf16x8 __attribute__((ext_vector_type(8)));
typedef bf16_t bf16x4 __attribute__((ext_vector_type(4)));
typedef float  floatx4 __attribute__((ext_vector_type(4)));

__device__ inline float dot4(float4 a, float4 b) {
    return a.x * b.x + a.y * b.y + a.z * b.z + a.w * b.w;
}

// ---------------------------------------------------------------------------
// prep: blocks [0,1024): fragment-major Hbf + hw.  One wave per 16-t tile.
//   frag layout: Hf[tile][kk][lane] = bf16x8 of H[t0 + (lane&15)][kk*32+(lane>>4)*8 ..+8]
//   -> main's B-fragment load is one coalesced 1024-B global_load_dwordx4 / wave.
// blocks [1024, 1024+4096): s2[b,a] = C_acts[b,a,:].c_utt[b,:] (wave per row)
// ---------------------------------------------------------------------------
__global__ __launch_bounds__(256) void prep_kernel(const float* __restrict__ H,
                                                   const float* __restrict__ W,
                                                   const float* __restrict__ Ca,
                                                   const float* __restrict__ cu,
                                                   float* __restrict__ hw,
                                                   bf16_t* __restrict__ Hf,
                                                   float* __restrict__ s2) {
    int wave = threadIdx.x >> 6;
    int lane = threadIdx.x & 63;
    if (blockIdx.x < 1024) {
        int tile = blockIdx.x * 4 + wave;        // [0, 4096) = b*32 + ti
        int b = tile >> 5, ti = tile & 31;
        int lrow = lane & 15, quad = lane >> 4;
        const float* hrow = H + ((size_t)b * T_ + ti * 16 + lrow) * D_;
        char* fdst = (char*)Hf + (size_t)tile * TILE_BYTES + lane * 16;
        float acc = 0.f;
#pragma unroll
        for (int kk = 0; kk < 13; ++kk) {
            int k0 = kk * 32 + quad * 8;
            bf16x8 f;
            if (k0 < D_) {
                float4 x = *(const float4*)(hrow + k0);
                float4 y = *(const float4*)(hrow + k0 + 4);
                float4 wx = *(const float4*)(W + k0);
                float4 wy = *(const float4*)(W + k0 + 4);
                acc += dot4(x, wx) + dot4(y, wy);
                f[0] = (bf16_t)x.x; f[1] = (bf16_t)x.y; f[2] = (bf16_t)x.z; f[3] = (bf16_t)x.w;
                f[4] = (bf16_t)y.x; f[5] = (bf16_t)y.y; f[6] = (bf16_t)y.z; f[7] = (bf16_t)y.w;
            } else {
#pragma unroll
                for (int j = 0; j < 8; ++j) f[j] = (bf16_t)0.0f;
            }
            *(bf16x8*)(fdst + kk * 1024) = f;
        }
        // sum the 4 quad partials for each lrow
        acc += __shfl_xor(acc, 16, 64);
        acc += __shfl_xor(acc, 32, 64);
        if (lane < 16) hw[b * T_ + ti * 16 + lane] = acc;
    } else {
        long row = (long)(blockIdx.x - 1024) * 4 + wave;   // [0, B*NA)
        int b = (int)(row >> 7);
        const float4* a4 = (const float4*)(Ca + row * (long)D_);
        const float4* c4 = (const float4*)(cu + (long)b * D_);
        float acc = dot4(a4[lane], c4[lane]);
        if (lane < 36) acc += dot4(a4[lane + 64], c4[lane + 64]);
#pragma unroll
        for (int off = 1; off < 64; off <<= 1) acc += __shfl_xor(acc, off, 64);
        if (lane == 0) s2[row] = acc;
    }
}

// ---------------------------------------------------------------------------
// qacts: per-b softmax of s2 + q_acts (barriers uniform — R4 bugfix retained)
// ---------------------------------------------------------------------------
__global__ __launch_bounds__(256) void qacts_kernel(const float* __restrict__ s2,
                                                    const float* __restrict__ Ca,
                                                    float* __restrict__ q_ws) {
    __shared__ float p_lds[NA];
    __shared__ float red[8];
    __shared__ __align__(16) float4 part[100];
    int b = blockIdx.x;
    int tid = threadIdx.x, wave = tid >> 6, lane = tid & 63;

    float s = (tid < NA) ? s2[(long)b * NA + tid] : -3.0e38f;
    float m = s;
#pragma unroll
    for (int off = 1; off < 64; off <<= 1) m = fmaxf(m, __shfl_xor(m, off, 64));
    if (lane == 0) red[wave] = m;
    __syncthreads();
    m = fmaxf(red[0], red[1]);
    float e = (tid < NA) ? __expf(s - m) : 0.f;
    float sum = e;
#pragma unroll
    for (int off = 1; off < 64; off <<= 1) sum += __shfl_xor(sum, off, 64);
    if (lane == 0) red[4 + wave] = sum;
    __syncthreads();
    float S = red[4] + red[5];
    if (tid < NA) p_lds[tid] = e / S;
    __syncthreads();

    int c4 = tid % 100;
    int half = tid / 100;
    float4 acc0 = {0.f, 0.f, 0.f, 0.f};
    if (tid < 200) {
        const float4* Cb4 = (const float4*)(Ca + (size_t)b * NA * D_);
        float4 acc1 = {0.f, 0.f, 0.f, 0.f};
        int a0 = half * 64;
#pragma unroll 4
        for (int a = 0; a < 64; a += 2) {
            float p0 = p_lds[a0 + a], p1 = p_lds[a0 + a + 1];
            float4 x0 = Cb4[(size_t)(a0 + a) * 100 + c4];
            float4 x1 = Cb4[(size_t)(a0 + a + 1) * 100 + c4];
            acc0.x += p0 * x0.x; acc0.y += p0 * x0.y; acc0.z += p0 * x0.z; acc0.w += p0 * x0.w;
            acc1.x += p1 * x1.x; acc1.y += p1 * x1.y; acc1.z += p1 * x1.z; acc1.w += p1 * x1.w;
        }
        acc0.x += acc1.x; acc0.y += acc1.y; acc0.z += acc1.z; acc0.w += acc1.w;
        if (half == 1) part[c4] = acc0;
    }
    __syncthreads();
    if (tid < 100) {
        float4 o = part[c4];
        o.x += acc0.x; o.y += acc0.y; o.z += acc0.z; o.w += acc0.w;
        ((float4*)(q_ws + (size_t)b * D_))[c4] = o;
    }
}

// ---------------------------------------------------------------------------
// Fused main + yacts. NO LDS, NO BARRIERS.
//   blocks [0,512): flash attention. Block = (b, 256-v chunk); wave = 64 v
//   (4 A-sets). Wave loops all 16-t tiles of b; B-fragments loaded straight
//   from fragment-major Hf with coalesced b128 loads, double-buffered.
//   1 wave/SIMD (VGPR ~390) — 4 indep MFMA chains hide latency in-wave.
//   blocks [512, +8192): y_acts (one wave per 4 v-rows).
// ---------------------------------------------------------------------------
#define LDTILE(BUF, TI)                                                        \
    _Pragma("unroll") for (int kk = 0; kk < 13; ++kk)                          \
        BUF[kk] = *(const bf16x8*)(fb + (size_t)(TI) * TILE_BYTES + kk * 1024);

#define COMPUTE(BUF, TI)                                                       \
    do {                                                                       \
        floatx4 c_[4];                                                         \
        _Pragma("unroll") for (int s_ = 0; s_ < 4; ++s_) c_[s_] = zero4;       \
        _Pragma("unroll") for (int kk = 0; kk < 13; ++kk) {                    \
            bf16x8 bb_ = BUF[kk];                                              \
            _Pragma("unroll") for (int s_ = 0; s_ < 4; ++s_)                   \
                c_[s_] = __builtin_amdgcn_mfma_f32_16x16x32_bf16(              \
                    afrag[s_][kk], bb_, c_[s_], 0, 0, 0);                      \
        }                                                                      \
        int t_ = (TI) * 16 + lrow;                                             \
        float hwv_ = hwb[t_];                                                  \
        bool ok_ = t_ < len;                                                   \
        float cm_ = -3.0e38f;                                                  \
        _Pragma("unroll") for (int s_ = 0; s_ < 4; ++s_)                       \
            _Pragma("unroll") for (int r_ = 0; r_ < 4; ++r_) {                 \
                float v_ = ok_ ? c_[s_][r_] : -3.0e38f;                        \
                c_[s_][r_] = v_;                                               \
                cm_ = fmaxf(cm_, v_);                                          \
            }                                                                  \
        float mn_ = fmaxf(m_s, cm_);                                           \
        float alpha_ = __expf(m_s - mn_);                                      \
        m_s = mn_;                                                             \
        _Pragma("unroll") for (int s_ = 0; s_ < 4; ++s_)                       \
            _Pragma("unroll") for (int r_ = 0; r_ < 4; ++r_) {                 \
                float p_ = __expf(c_[s_][r_] - mn_);                           \
                l_s[s_][r_] = l_s[s_][r_] * alpha_ + p_;                       \
                a_s[s_][r_] = a_s[s_][r_] * alpha_ + p_ * hwv_;                \
            }                                                                  \
    } while (0)

__global__ __launch_bounds__(256, 1) void main_kernel(const bf16_t* __restrict__ Hf,
                                                      const float* __restrict__ Cv,
                                                      const float* __restrict__ hw,
                                                      const float* __restrict__ bs,
                                                      const int* __restrict__ lens,
                                                      const float* __restrict__ q_ws,
                                                      float* __restrict__ out) {
    int tid = threadIdx.x;
    int wave = tid >> 6, lane = tid & 63;

    if (blockIdx.x >= MAIN_BLOCKS) {
        // ---- yacts part ----
        long grp = (long)(blockIdx.x - MAIN_BLOCKS) * 4 + wave;   // [0, B*NV/4)
        int b = (int)(grp >> 8);
        int v0 = (int)(grp & 255) * 4;
        const float4* q4 = (const float4*)(q_ws + (size_t)b * D_);
        float4 qa = q4[lane];
        float4 qb = (lane < 36) ? q4[lane + 64] : make_float4(0.f, 0.f, 0.f, 0.f);
        float acc[4];
#pragma unroll
        for (int r = 0; r < 4; ++r) {
            const float4* v4 = (const float4*)(Cv + (size_t)(v0 + r) * D_);
            acc[r] = dot4(v4[lane], qa);
            if (lane < 36) acc[r] += dot4(v4[lane + 64], qb);
        }
#pragma unroll
        for (int off = 1; off < 64; off <<= 1) {
#pragma unroll
            for (int r = 0; r < 4; ++r) acc[r] += __shfl_xor(acc[r], off, 64);
        }
        if (lane == 0) {
            float4 o = make_float4(acc[0], acc[1], acc[2], acc[3]);
            *(float4*)(out + (size_t)B_ * NV + (size_t)b * NV + v0) = o;
        }
        return;
    }

    // ---- attention part ----
    int i = blockIdx.x;
    int xcd = i & 7, vc = (i >> 3) & 3, bb = i >> 5;
    int b = xcd + 8 * bb;                 // 8 co-XCD blocks share one b's Hf
    int vbase = vc * 256 + wave * 64;

    int lrow = lane & 15, quad = lane >> 4;
    int len = lens[b];
    float b0 = bs[0];

    // A fragments: 4 sets x 13 k-steps (vals rows f32 -> bf16), 208 VGPRs
    bf16x8 afrag[4][13];
#pragma unroll
    for (int set = 0; set < 4; ++set) {
        const float* vrow = Cv + (size_t)(vbase + set * 16 + lrow) * D_;
#pragma unroll
        for (int kk = 0; kk < 13; ++kk) {
            int k0 = kk * 32 + quad * 8;
            bf16x8 f;
            if (k0 >= D_) {
#pragma unroll
                for (int j = 0; j < 8; ++j) f[j] = (bf16_t)0.0f;
            } else {
                const float4* p = (const float4*)(vrow + k0);
                float4 x = p[0], y = p[1];
                f[0] = (bf16_t)x.x; f[1] = (bf16_t)x.y;
                f[2] = (bf16_t)x.z; f[3] = (bf16_t)x.w;
                f[4] = (bf16_t)y.x; f[5] = (bf16_t)y.y;
                f[6] = (bf16_t)y.z; f[7] = (bf16_t)y.w;
            }
            afrag[set][kk] = f;
        }
    }

    float m_s = -3.0e38f;
    float l_s[4][4], a_s[4][4];
#pragma unroll
    for (int s = 0; s < 4; ++s)
#pragma unroll
        for (int r = 0; r < 4; ++r) { l_s[s][r] = 0.f; a_s[s][r] = 0.f; }

    const floatx4 zero4 = {0.f, 0.f, 0.f, 0.f};
    const float* hwb = hw + (size_t)b * T_;
    const char* fb = (const char*)Hf + (size_t)b * 32 * TILE_BYTES + lane * 16;

    int ntiles = (len + 15) >> 4;   // uniform per block; len >= 256 -> >= 16
    bf16x8 bfA[13], bfB[13];

    LDTILE(bfA, 0);
    int ti = 0;
    while (true) {
        if (ti + 1 < ntiles) { LDTILE(bfB, ti + 1); }
        COMPUTE(bfA, ti);
        ++ti; if (ti == ntiles) break;
        if (ti + 1 < ntiles) { LDTILE(bfA, ti + 1); }
        COMPUTE(bfB, ti);
        ++ti; if (ti == ntiles) break;
    }

    // epilogue: butterfly-merge the 16 per-lane column states per row
#pragma unroll
    for (int s = 0; s < 4; ++s)
#pragma unroll
        for (int r = 0; r < 4; ++r) {
            float m = m_s, l = l_s[s][r], a = a_s[s][r];
#pragma unroll
            for (int off = 1; off < 16; off <<= 1) {
                float mo = __shfl_xor(m, off, 64);
                float lo = __shfl_xor(l, off, 64);
                float ao = __shfl_xor(a, off, 64);
                float mx = fmaxf(m, mo);
                float f1 = __expf(m - mx), f2 = __expf(mo - mx);
                l = l * f1 + lo * f2;
                a = a * f1 + ao * f2;
                m = mx;
            }
            if (lrow == 0) {
                int v = vbase + s * 16 + quad * 4 + r;
                out[(size_t)b * NV + v] = a / l + b0;
            }
        }
}

// ---------------------------------------------------------------------------
// Fallback path (workspace too small): R6's LDS-based fused kernel + prep.
// ---------------------------------------------------------------------------
__global__ __launch_bounds__(256) void prep_fb_kernel(const float* __restrict__ H,
                                                      const float* __restrict__ W,
                                                      const float* __restrict__ Ca,
                                                      const float* __restrict__ cu,
                                                      float* __restrict__ hw,
                                                      float* __restrict__ s2) {
    int wave = threadIdx.x >> 6;
    int lane = threadIdx.x & 63;
    if (blockIdx.x < B_ * T_ / 4) {
        long row = (long)blockIdx.x * 4 + wave;
        const float* h = H + row * D_;
        float acc = 0.f;
        for (int k = lane; k < D_; k += 64) acc += h[k] * W[k];
#pragma unroll
        for (int off = 1; off < 64; off <<= 1) acc += __shfl_xor(acc, off, 64);
        if (lane == 0) hw[row] = acc;
    } else {
        long row = (long)(blockIdx.x - B_ * T_ / 4) * 4 + wave;
        int b = (int)(row >> 7);
        const float4* a4 = (const float4*)(Ca + row * (long)D_);
        const float4* c4 = (const float4*)(cu + (long)b * D_);
        float acc = dot4(a4[lane], c4[lane]);
        if (lane < 36) acc += dot4(a4[lane + 64], c4[lane + 64]);
#pragma unroll
        for (int off = 1; off < 64; off <<= 1) acc += __shfl_xor(acc, off, 64);
        if (lane == 0) s2[row] = acc;
    }
}

__global__ __launch_bounds__(256, 2) void main_fb_kernel(const float* __restrict__ H,
                                                         const float* __restrict__ Cv,
                                                         const float* __restrict__ hw,
                                                         const float* __restrict__ bs,
                                                         const int* __restrict__ lens,
                                                         const float* __restrict__ q_ws,
                                                         float* __restrict__ out) {
    __shared__ bf16_t h_lds[NT * LDH];
    __shared__ float hw_lds[NT];

    int tid = threadIdx.x;
    int wave = tid >> 6, lane = tid & 63;

    if (blockIdx.x >= FB_MAIN_BLOCKS) {
        long grp = (long)(blockIdx.x - FB_MAIN_BLOCKS) * 4 + wave;
        int b = (int)(grp >> 8);
        int v0 = (int)(grp & 255) * 4;
        const float4* q4 = (const float4*)(q_ws + (size_t)b * D_);
        float4 qa = q4[lane];
        float4 qb = (lane < 36) ? q4[lane + 64] : make_float4(0.f, 0.f, 0.f, 0.f);
        float acc[4];
#pragma unroll
        for (int r = 0; r < 4; ++r) {
            const float4* v4 = (const float4*)(Cv + (size_t)(v0 + r) * D_);
            acc[r] = dot4(v4[lane], qa);
            if (lane < 36) acc[r] += dot4(v4[lane + 64], qb);
        }
#pragma unroll
        for (int off = 1; off < 64; off <<= 1) {
#pragma unroll
            for (int r = 0; r < 4; ++r) acc[r] += __shfl_xor(acc[r], off, 64);
        }
        if (lane == 0) {
            float4 o = make_float4(acc[0], acc[1], acc[2], acc[3]);
            *(float4*)(out + (size_t)B_ * NV + (size_t)b * NV + v0) = o;
        }
        return;
    }

    int i = blockIdx.x;
    int xcd = i & 7, vc = (i >> 3) & 7, bb = i >> 6;
    int b = xcd + 8 * bb;
    int vbase = vc * 128;

    int lrow = lane & 15, quad = lane >> 4;
    int len = lens[b];
    float b0 = bs[0];

    for (int idx = tid; idx < NT * (LDH - D_); idx += 256) {
        int r = idx / (LDH - D_), c = idx % (LDH - D_);
        h_lds[r * LDH + D_ + c] = (bf16_t)0.0f;
    }

    bf16x8 afrag[2][13];
#pragma unroll
    for (int set = 0; set < 2; ++set) {
        const float* vrow = Cv + (size_t)(vbase + wave * 32 + set * 16 + lrow) * D_;
#pragma unroll
        for (int kk = 0; kk < 13; ++kk) {
            int k0 = kk * 32 + quad * 8;
            bf16x8 f;
            if (k0 >= D_) {
#pragma unroll
                for (int j = 0; j < 8; ++j) f[j] = (bf16_t)0.0f;
            } else {
                const float4* p = (const float4*)(vrow + k0);
                float4 x = p[0], y = p[1];
                f[0] = (bf16_t)x.x; f[1] = (bf16_t)x.y;
                f[2] = (bf16_t)x.z; f[3] = (bf16_t)x.w;
                f[4] = (bf16_t)y.x; f[5] = (bf16_t)y.y;
                f[6] = (bf16_t)y.z; f[7] = (bf16_t)y.w;
            }
            afrag[set][kk] = f;
        }
    }

    float m_s = -3.0e38f;
    float l_s[2][4], a_s[2][4];
#pragma unroll
    for (int set = 0; set < 2; ++set)
#pragma unroll
        for (int r = 0; r < 4; ++r) { l_s[set][r] = 0.f; a_s[set][r] = 0.f; }

    int ntiles = (len + NT - 1) / NT;
    const float* Hb = H + (size_t)b * T_ * D_;

    for (int tt = 0; tt < ntiles; ++tt) {
        int t0 = tt * NT;
        __syncthreads();
        for (int idx = tid; idx < NT * (D_ / 4); idx += 256) {
            int r = idx / (D_ / 4), c4 = idx % (D_ / 4);
            float4 x = *(const float4*)(Hb + (size_t)(t0 + r) * D_ + c4 * 4);
            bf16x4 f;
            f[0] = (bf16_t)x.x; f[1] = (bf16_t)x.y;
            f[2] = (bf16_t)x.z; f[3] = (bf16_t)x.w;
            *(bf16x4*)(&h_lds[r * LDH + c4 * 4]) = f;
        }
        if (tid < NT) hw_lds[tid] = hw[(size_t)b * T_ + t0 + tid];
        __syncthreads();

        floatx4 c[2][2];
        floatx4 zero4 = {0.f, 0.f, 0.f, 0.f};
#pragma unroll
        for (int set = 0; set < 2; ++set)
#pragma unroll
            for (int s = 0; s < 2; ++s) c[set][s] = zero4;

#pragma unroll
        for (int kk = 0; kk < 13; ++kk) {
            int koff = kk * 32 + quad * 8;
#pragma unroll
            for (int s = 0; s < 2; ++s) {
                bf16x8 bfr = *(const bf16x8*)(&h_lds[(s * 16 + lrow) * LDH + koff]);
                c[0][s] = __builtin_amdgcn_mfma_f32_16x16x32_bf16(afrag[0][kk], bfr, c[0][s], 0, 0, 0);
                c[1][s] = __builtin_amdgcn_mfma_f32_16x16x32_bf16(afrag[1][kk], bfr, c[1][s], 0, 0, 0);
            }
        }

        if (t0 + NT > len) {
#pragma unroll
            for (int s = 0; s < 2; ++s) {
                int t = t0 + s * 16 + lrow;
                if (t >= len) {
#pragma unroll
                    for (int set = 0; set < 2; ++set) {
                        c[set][s][0] = -3.0e38f; c[set][s][1] = -3.0e38f;
                        c[set][s][2] = -3.0e38f; c[set][s][3] = -3.0e38f;
                    }
                }
            }
        }

        float hw0 = hw_lds[lrow], hw1 = hw_lds[16 + lrow];
        float cm = -3.0e38f;
#pragma unroll
        for (int set = 0; set < 2; ++set)
#pragma unroll
            for (int s = 0; s < 2; ++s)
#pragma unroll
                for (int r = 0; r < 4; ++r) cm = fmaxf(cm, c[set][s][r]);
        float mn = fmaxf(m_s, cm);
        float alpha = __expf(m_s - mn);
        m_s = mn;
#pragma unroll
        for (int set = 0; set < 2; ++set)
#pragma unroll
            for (int r = 0; r < 4; ++r) {
                float p0 = __expf(c[set][0][r] - mn);
                float p1 = __expf(c[set][1][r] - mn);
                l_s[set][r] = l_s[set][r] * alpha + (p0 + p1);
                a_s[set][r] = a_s[set][r] * alpha + (p0 * hw0 + p1 * hw1);
            }
    }

#pragma unroll
    for (int set = 0; set < 2; ++set)
#pragma unroll
        for (int r = 0; r < 4; ++r) {
            float m = m_s, l = l_s[set][r], a = a_s[set][r];
#pragma unroll
            for (int off = 1; off < 16; off <<= 1) {
                float mo = __shfl_xor(m, off, 64);
                float lo = __shfl_xor(l, off, 64);
                float ao = __shfl_xor(a, off, 64);
                float mx = fmaxf(m, mo);
                float f1 = __expf(m - mx), f2 = __expf(mo - mx);
                l = l * f1 + lo * f2;
                a = a * f1 + ao * f2;
                m = mx;
            }
            if (lrow == 0) {
                int v = vbase + wave * 32 + set * 16 + quad * 4 + r;
                out[(size_t)b * NV + v] = a / l + b0;
            }
        }
}

// ---------------------------------------------------------------------------
extern "C" void kernel_launch(void* const* d_in, const int* in_sizes, int n_in,
                              void* d_out, int out_size, void* d_ws, size_t ws_size,
                              hipStream_t stream) {
    const float* H    = (const float*)d_in[0];   // (B,T,D)
    const float* cu   = (const float*)d_in[1];   // (B,D)
    const float* Ca   = (const float*)d_in[2];   // (B,NA,D)
    const float* Cv   = (const float*)d_in[3];   // (NV,1,D)
    const float* W    = (const float*)d_in[4];   // (1,D)
    const float* bs   = (const float*)d_in[5];   // (1,)
    const int*   lens = (const int*)d_in[6];     // (B,)
    float* out = (float*)d_out;                  // f32: y_utts (B,NV) ++ y_acts (B,NV)

    float*  hw   = (float*)d_ws;                        // B*T f32 (256 KB)
    float*  q_ws = hw + (size_t)B_ * T_;                // B*D f32 (200 KB)
    float*  s2   = q_ws + (size_t)B_ * D_;              // B*NA f32 (64 KB)
    bf16_t* Hf   = (bf16_t*)(s2 + (size_t)B_ * NA);     // 4096 tiles x 13312 B (54.5 MB)

    size_t need = ((size_t)B_ * T_ + (size_t)B_ * D_ + (size_t)B_ * NA) * sizeof(float)
                + (size_t)4096 * TILE_BYTES;
    bool pre = (ws_size >= need);

    if (pre) {
        prep_kernel<<<dim3(1024 + B_ * NA / 4), dim3(256), 0, stream>>>(H, W, Ca, cu, hw, Hf, s2);
        qacts_kernel<<<dim3(B_), dim3(256), 0, stream>>>(s2, Ca, q_ws);
        main_kernel<<<dim3(MAIN_BLOCKS + B_ * NV / 16), dim3(256), 0, stream>>>(Hf, Cv, hw, bs, lens, q_ws, out);
    } else {
        prep_fb_kernel<<<dim3(B_ * T_ / 4 + B_ * NA / 4), dim3(256), 0, stream>>>(H, W, Ca, cu, hw, s2);
        qacts_kernel<<<dim3(B_), dim3(256), 0, stream>>>(s2, Ca, q_ws);
        main_fb_kernel<<<dim3(FB_MAIN_BLOCKS + B_ * NV / 16), dim3(256), 0, stream>>>(H, Cv, hw, bs, lens, q_ws, out);
    }
}

// Round 8
// 298.810 us; speedup vs baseline: 1.0523x; 1.0523x over previous
//
#include <hip/hip_runtime.h>
#include <hip/hip_bf16.h>

// Problem constants
#define B_  128
#define T_  512
#define D_  400
#define NV  1024
#define NA  128

#define TILE_BYTES 13312          // 13 kk-blocks x 1024 B per 16-t fragment-major tile
#define STEP_BYTES 26624          // 32-t step = 2 tiles
#define ATTN_BLOCKS 512           // 128 b x 4 v-chunks of 256

// Fallback (no-workspace) tiling
#define LDH  424
#define NT_FB 32
#define FB_MAIN_BLOCKS 1024

typedef __bf16 bf16_t;
typedef bf16_t bf16x8 __attribute__((ext_vector_type(8)));
typedef bf16_t bf16x4 __attribute__((ext_vector_type(4)));
typedef float  floatx4 __attribute__((ext_vector_type(4)));

__device__ inline void async_copy16(const void* g, void* l) {
    __builtin_amdgcn_global_load_lds(
        (const __attribute__((address_space(1))) unsigned int*)g,
        (__attribute__((address_space(3))) unsigned int*)l, 16, 0, 0);
}

__device__ inline float dot4(float4 a, float4 b) {
    return a.x * b.x + a.y * b.y + a.z * b.z + a.w * b.w;
}

// ---------------------------------------------------------------------------
// prep: blocks [0,1024): fragment-major Hf + hw.  One wave per 16-t tile.
//   Hf[tile][kk][lane] = bf16x8 of H[t0+(lane&15)][kk*32+(lane>>4)*8 ..+8]
// blocks [1024, +4096): s2[b,a] = C_acts[b,a,:].c_utt[b,:] (wave per row)
// ---------------------------------------------------------------------------
__global__ __launch_bounds__(256) void prep_kernel(const float* __restrict__ H,
                                                   const float* __restrict__ W,
                                                   const float* __restrict__ Ca,
                                                   const float* __restrict__ cu,
                                                   float* __restrict__ hw,
                                                   bf16_t* __restrict__ Hf,
                                                   float* __restrict__ s2) {
    int wave = threadIdx.x >> 6;
    int lane = threadIdx.x & 63;
    if (blockIdx.x < 1024) {
        int tile = blockIdx.x * 4 + wave;        // [0, 4096) = b*32 + ti
        int b = tile >> 5, ti = tile & 31;
        int lrow = lane & 15, quad = lane >> 4;
        const float* hrow = H + ((size_t)b * T_ + ti * 16 + lrow) * D_;
        char* fdst = (char*)Hf + (size_t)tile * TILE_BYTES + lane * 16;
        float acc = 0.f;
#pragma unroll
        for (int kk = 0; kk < 13; ++kk) {
            int k0 = kk * 32 + quad * 8;
            bf16x8 f;
            if (k0 < D_) {
                float4 x = *(const float4*)(hrow + k0);
                float4 y = *(const float4*)(hrow + k0 + 4);
                float4 wx = *(const float4*)(W + k0);
                float4 wy = *(const float4*)(W + k0 + 4);
                acc += dot4(x, wx) + dot4(y, wy);
                f[0] = (bf16_t)x.x; f[1] = (bf16_t)x.y; f[2] = (bf16_t)x.z; f[3] = (bf16_t)x.w;
                f[4] = (bf16_t)y.x; f[5] = (bf16_t)y.y; f[6] = (bf16_t)y.z; f[7] = (bf16_t)y.w;
            } else {
#pragma unroll
                for (int j = 0; j < 8; ++j) f[j] = (bf16_t)0.0f;
            }
            *(bf16x8*)(fdst + kk * 1024) = f;
        }
        acc += __shfl_xor(acc, 16, 64);
        acc += __shfl_xor(acc, 32, 64);
        if (lane < 16) hw[b * T_ + ti * 16 + lane] = acc;
    } else {
        long row = (long)(blockIdx.x - 1024) * 4 + wave;   // [0, B*NA)
        int b = (int)(row >> 7);
        const float4* a4 = (const float4*)(Ca + row * (long)D_);
        const float4* c4 = (const float4*)(cu + (long)b * D_);
        float acc = dot4(a4[lane], c4[lane]);
        if (lane < 36) acc += dot4(a4[lane + 64], c4[lane + 64]);
#pragma unroll
        for (int off = 1; off < 64; off <<= 1) acc += __shfl_xor(acc, off, 64);
        if (lane == 0) s2[row] = acc;
    }
}

// ---------------------------------------------------------------------------
// qacts: per-b softmax of s2 + q_acts (barriers uniform — R4 bugfix retained)
// ---------------------------------------------------------------------------
__global__ __launch_bounds__(256) void qacts_kernel(const float* __restrict__ s2,
                                                    const float* __restrict__ Ca,
                                                    float* __restrict__ q_ws) {
    __shared__ float p_lds[NA];
    __shared__ float red[8];
    __shared__ __align__(16) float4 part[100];
    int b = blockIdx.x;
    int tid = threadIdx.x, wave = tid >> 6, lane = tid & 63;

    float s = (tid < NA) ? s2[(long)b * NA + tid] : -3.0e38f;
    float m = s;
#pragma unroll
    for (int off = 1; off < 64; off <<= 1) m = fmaxf(m, __shfl_xor(m, off, 64));
    if (lane == 0) red[wave] = m;
    __syncthreads();
    m = fmaxf(red[0], red[1]);
    float e = (tid < NA) ? __expf(s - m) : 0.f;
    float sum = e;
#pragma unroll
    for (int off = 1; off < 64; off <<= 1) sum += __shfl_xor(sum, off, 64);
    if (lane == 0) red[4 + wave] = sum;
    __syncthreads();
    float S = red[4] + red[5];
    if (tid < NA) p_lds[tid] = e / S;
    __syncthreads();

    int c4 = tid % 100;
    int half = tid / 100;
    float4 acc0 = {0.f, 0.f, 0.f, 0.f};
    if (tid < 200) {
        const float4* Cb4 = (const float4*)(Ca + (size_t)b * NA * D_);
        float4 acc1 = {0.f, 0.f, 0.f, 0.f};
        int a0 = half * 64;
#pragma unroll 4
        for (int a = 0; a < 64; a += 2) {
            float p0 = p_lds[a0 + a], p1 = p_lds[a0 + a + 1];
            float4 x0 = Cb4[(size_t)(a0 + a) * 100 + c4];
            float4 x1 = Cb4[(size_t)(a0 + a + 1) * 100 + c4];
            acc0.x += p0 * x0.x; acc0.y += p0 * x0.y; acc0.z += p0 * x0.z; acc0.w += p0 * x0.w;
            acc1.x += p1 * x1.x; acc1.y += p1 * x1.y; acc1.z += p1 * x1.z; acc1.w += p1 * x1.w;
        }
        acc0.x += acc1.x; acc0.y += acc1.y; acc0.z += acc1.z; acc0.w += acc1.w;
        if (half == 1) part[c4] = acc0;
    }
    __syncthreads();
    if (tid < 100) {
        float4 o = part[c4];
        o.x += acc0.x; o.y += acc0.y; o.z += acc0.z; o.w += acc0.w;
        ((float4*)(q_ws + (size_t)b * D_))[c4] = o;
    }
}

// ---------------------------------------------------------------------------
// yacts: one wave per 4 v-rows (separate kernel: no LDS -> full occupancy)
// ---------------------------------------------------------------------------
__global__ __launch_bounds__(256) void yacts_kernel(const float* __restrict__ q_ws,
                                                    const float* __restrict__ Cv,
                                                    float* __restrict__ out) {
    int wave = threadIdx.x >> 6;
    int lane = threadIdx.x & 63;
    long grp = (long)blockIdx.x * 4 + wave;          // [0, B*NV/4)
    int b = (int)(grp >> 8);
    int v0 = (int)(grp & 255) * 4;
    const float4* q4 = (const float4*)(q_ws + (size_t)b * D_);
    float4 qa = q4[lane];
    float4 qb = (lane < 36) ? q4[lane + 64] : make_float4(0.f, 0.f, 0.f, 0.f);
    float acc[4];
#pragma unroll
    for (int r = 0; r < 4; ++r) {
        const float4* v4 = (const float4*)(Cv + (size_t)(v0 + r) * D_);
        acc[r] = dot4(v4[lane], qa);
        if (lane < 36) acc[r] += dot4(v4[lane + 64], qb);
    }
#pragma unroll
    for (int off = 1; off < 64; off <<= 1) {
#pragma unroll
        for (int r = 0; r < 4; ++r) acc[r] += __shfl_xor(acc[r], off, 64);
    }
    if (lane == 0) {
        float4 o = make_float4(acc[0], acc[1], acc[2], acc[3]);
        *(float4*)(out + (size_t)B_ * NV + (size_t)b * NV + v0) = o;
    }
}

// ---------------------------------------------------------------------------
// Attention kernel. 1 block/CU, 4 waves x 4 A-sets (64 v/wave, 256 v/block).
// H tiles (fragment-major Hf) double-buffer-staged into LDS via
// global_load_lds; one barrier per 32-t step; the barrier's implicit vmcnt
// drain covers the stage issued ~2000 cyc earlier (free). Each ds_read_b128
// B-fragment feeds 4 MFMAs; 8 independent accumulator chains.
// ---------------------------------------------------------------------------
__global__ __launch_bounds__(256, 1) void attn_kernel(const bf16_t* __restrict__ Hf,
                                                      const float* __restrict__ Cv,
                                                      const float* __restrict__ hw,
                                                      const float* __restrict__ bs,
                                                      const int* __restrict__ lens,
                                                      float* __restrict__ out) {
    __shared__ __align__(16) char lds[2][STEP_BYTES];

    int tid = threadIdx.x;
    int wave = tid >> 6, lane = tid & 63;
    int lrow = lane & 15, quad = lane >> 4;

    // XCD swizzle: 4 v-chunks of one b + 8 b's per XCD -> Hf[b] L2-resident
    int i = blockIdx.x;
    int xcd = i & 7, vc = (i >> 3) & 3, bb = i >> 5;
    int b = xcd + 8 * bb;                 // 0..127
    int vbase = vc * 256 + wave * 64;

    int len = lens[b];
    float b0 = bs[0];

    // A fragments: 4 sets x 13 k-steps (vals rows f32 -> bf16), ~208 regs
    bf16x8 afrag[4][13];
#pragma unroll
    for (int set = 0; set < 4; ++set) {
        const float* vrow = Cv + (size_t)(vbase + set * 16 + lrow) * D_;
#pragma unroll
        for (int kk = 0; kk < 13; ++kk) {
            int k0 = kk * 32 + quad * 8;
            bf16x8 f;
            if (k0 >= D_) {
#pragma unroll
                for (int j = 0; j < 8; ++j) f[j] = (bf16_t)0.0f;
            } else {
                const float4* p = (const float4*)(vrow + k0);
                float4 x = p[0], y = p[1];
                f[0] = (bf16_t)x.x; f[1] = (bf16_t)x.y;
                f[2] = (bf16_t)x.z; f[3] = (bf16_t)x.w;
                f[4] = (bf16_t)y.x; f[5] = (bf16_t)y.y;
                f[6] = (bf16_t)y.z; f[7] = (bf16_t)y.w;
            }
            afrag[set][kk] = f;
        }
    }

    // per-lane shared-max online softmax state
    float m_s = -3.0e38f;
    float l_s[4][4], a_s[4][4];
#pragma unroll
    for (int s = 0; s < 4; ++s)
#pragma unroll
        for (int r = 0; r < 4; ++r) { l_s[s][r] = 0.f; a_s[s][r] = 0.f; }

    const char* fb = (const char*)Hf + (size_t)b * 32 * TILE_BYTES;
    const float* hwb = hw + (size_t)b * T_;
    int nsteps = (len + 31) >> 5;        // 8..16, uniform per block

    // pre-stage step 0
#pragma unroll 1
    for (int c = wave; c < 26; c += 4)
        async_copy16(fb + c * 1024 + lane * 16, lds[0] + c * 1024 + lane * 16);

    for (int tt = 0; tt < nsteps; ++tt) {
        __syncthreads();                 // drains the stage issued last iter (free)
        if (tt + 1 < nsteps) {
            const char* gs = fb + (size_t)(tt + 1) * STEP_BYTES;
            char* ls = lds[(tt + 1) & 1];
#pragma unroll 1
            for (int c = wave; c < 26; c += 4)
                async_copy16(gs + c * 1024 + lane * 16, ls + c * 1024 + lane * 16);
        }

        const char* lb = lds[tt & 1] + lane * 16;
        floatx4 c[4][2];
        const floatx4 zero4 = {0.f, 0.f, 0.f, 0.f};
#pragma unroll
        for (int s = 0; s < 4; ++s) { c[s][0] = zero4; c[s][1] = zero4; }

#pragma unroll
        for (int kk = 0; kk < 13; ++kk) {
            bf16x8 b0 = *(const bf16x8*)(lb + kk * 1024);
            bf16x8 b1 = *(const bf16x8*)(lb + TILE_BYTES + kk * 1024);
#pragma unroll
            for (int set = 0; set < 4; ++set) {
                c[set][0] = __builtin_amdgcn_mfma_f32_16x16x32_bf16(afrag[set][kk], b0, c[set][0], 0, 0, 0);
                c[set][1] = __builtin_amdgcn_mfma_f32_16x16x32_bf16(afrag[set][kk], b1, c[set][1], 0, 0, 0);
            }
        }

        int t0 = tt * 32;
        if (t0 + 32 > len) {             // tail mask: col t = t0 + s*16 + lrow
#pragma unroll
            for (int s = 0; s < 2; ++s) {
                int t = t0 + s * 16 + lrow;
                if (t >= len) {
#pragma unroll
                    for (int set = 0; set < 4; ++set) {
                        c[set][s][0] = -3.0e38f; c[set][s][1] = -3.0e38f;
                        c[set][s][2] = -3.0e38f; c[set][s][3] = -3.0e38f;
                    }
                }
            }
        }

        float hw0 = hwb[t0 + lrow];
        float hw1 = hwb[t0 + 16 + lrow];

        float cm = -3.0e38f;
#pragma unroll
        for (int set = 0; set < 4; ++set)
#pragma unroll
            for (int s = 0; s < 2; ++s)
#pragma unroll
                for (int r = 0; r < 4; ++r) cm = fmaxf(cm, c[set][s][r]);
        float mn = fmaxf(m_s, cm);
        float alpha = __expf(m_s - mn);
        m_s = mn;
#pragma unroll
        for (int set = 0; set < 4; ++set)
#pragma unroll
            for (int r = 0; r < 4; ++r) {
                float p0 = __expf(c[set][0][r] - mn);
                float p1 = __expf(c[set][1][r] - mn);
                l_s[set][r] = l_s[set][r] * alpha + (p0 + p1);
                a_s[set][r] = a_s[set][r] * alpha + (p0 * hw0 + p1 * hw1);
            }
    }

    // epilogue: butterfly-merge the 16 per-lane column states per row
#pragma unroll
    for (int set = 0; set < 4; ++set)
#pragma unroll
        for (int r = 0; r < 4; ++r) {
            float m = m_s, l = l_s[set][r], a = a_s[set][r];
#pragma unroll
            for (int off = 1; off < 16; off <<= 1) {
                float mo = __shfl_xor(m, off, 64);
                float lo = __shfl_xor(l, off, 64);
                float ao = __shfl_xor(a, off, 64);
                float mx = fmaxf(m, mo);
                float f1 = __expf(m - mx), f2 = __expf(mo - mx);
                l = l * f1 + lo * f2;
                a = a * f1 + ao * f2;
                m = mx;
            }
            if (lrow == 0) {
                int v = vbase + set * 16 + quad * 4 + r;
                out[(size_t)b * NV + v] = a / l + b0;
            }
        }
}

// ---------------------------------------------------------------------------
// Fallback path (workspace too small): R6-style LDS kernel + prep.
// ---------------------------------------------------------------------------
__global__ __launch_bounds__(256) void prep_fb_kernel(const float* __restrict__ H,
                                                      const float* __restrict__ W,
                                                      const float* __restrict__ Ca,
                                                      const float* __restrict__ cu,
                                                      float* __restrict__ hw,
                                                      float* __restrict__ s2) {
    int wave = threadIdx.x >> 6;
    int lane = threadIdx.x & 63;
    if (blockIdx.x < B_ * T_ / 4) {
        long row = (long)blockIdx.x * 4 + wave;
        const float* h = H + row * D_;
        float acc = 0.f;
        for (int k = lane; k < D_; k += 64) acc += h[k] * W[k];
#pragma unroll
        for (int off = 1; off < 64; off <<= 1) acc += __shfl_xor(acc, off, 64);
        if (lane == 0) hw[row] = acc;
    } else {
        long row = (long)(blockIdx.x - B_ * T_ / 4) * 4 + wave;
        int b = (int)(row >> 7);
        const float4* a4 = (const float4*)(Ca + row * (long)D_);
        const float4* c4 = (const float4*)(cu + (long)b * D_);
        float acc = dot4(a4[lane], c4[lane]);
        if (lane < 36) acc += dot4(a4[lane + 64], c4[lane + 64]);
#pragma unroll
        for (int off = 1; off < 64; off <<= 1) acc += __shfl_xor(acc, off, 64);
        if (lane == 0) s2[row] = acc;
    }
}

__global__ __launch_bounds__(256, 2) void main_fb_kernel(const float* __restrict__ H,
                                                         const float* __restrict__ Cv,
                                                         const float* __restrict__ hw,
                                                         const float* __restrict__ bs,
                                                         const int* __restrict__ lens,
                                                         float* __restrict__ out) {
    __shared__ bf16_t h_lds[NT_FB * LDH];
    __shared__ float hw_lds[NT_FB];

    int tid = threadIdx.x;
    int wave = tid >> 6, lane = tid & 63;

    int i = blockIdx.x;
    int xcd = i & 7, vc = (i >> 3) & 7, bb = i >> 6;
    int b = xcd + 8 * bb;
    int vbase = vc * 128;

    int lrow = lane & 15, quad = lane >> 4;
    int len = lens[b];
    float b0 = bs[0];

    for (int idx = tid; idx < NT_FB * (LDH - D_); idx += 256) {
        int r = idx / (LDH - D_), c = idx % (LDH - D_);
        h_lds[r * LDH + D_ + c] = (bf16_t)0.0f;
    }

    bf16x8 afrag[2][13];
#pragma unroll
    for (int set = 0; set < 2; ++set) {
        const float* vrow = Cv + (size_t)(vbase + wave * 32 + set * 16 + lrow) * D_;
#pragma unroll
        for (int kk = 0; kk < 13; ++kk) {
            int k0 = kk * 32 + quad * 8;
            bf16x8 f;
            if (k0 >= D_) {
#pragma unroll
                for (int j = 0; j < 8; ++j) f[j] = (bf16_t)0.0f;
            } else {
                const float4* p = (const float4*)(vrow + k0);
                float4 x = p[0], y = p[1];
                f[0] = (bf16_t)x.x; f[1] = (bf16_t)x.y;
                f[2] = (bf16_t)x.z; f[3] = (bf16_t)x.w;
                f[4] = (bf16_t)y.x; f[5] = (bf16_t)y.y;
                f[6] = (bf16_t)y.z; f[7] = (bf16_t)y.w;
            }
            afrag[set][kk] = f;
        }
    }

    float m_s = -3.0e38f;
    float l_s[2][4], a_s[2][4];
#pragma unroll
    for (int set = 0; set < 2; ++set)
#pragma unroll
        for (int r = 0; r < 4; ++r) { l_s[set][r] = 0.f; a_s[set][r] = 0.f; }

    int ntiles = (len + NT_FB - 1) / NT_FB;
    const float* Hb = H + (size_t)b * T_ * D_;

    for (int tt = 0; tt < ntiles; ++tt) {
        int t0 = tt * NT_FB;
        __syncthreads();
        for (int idx = tid; idx < NT_FB * (D_ / 4); idx += 256) {
            int r = idx / (D_ / 4), c4 = idx % (D_ / 4);
            float4 x = *(const float4*)(Hb + (size_t)(t0 + r) * D_ + c4 * 4);
            bf16x4 f;
            f[0] = (bf16_t)x.x; f[1] = (bf16_t)x.y;
            f[2] = (bf16_t)x.z; f[3] = (bf16_t)x.w;
            *(bf16x4*)(&h_lds[r * LDH + c4 * 4]) = f;
        }
        if (tid < NT_FB) hw_lds[tid] = hw[(size_t)b * T_ + t0 + tid];
        __syncthreads();

        floatx4 c[2][2];
        floatx4 zero4 = {0.f, 0.f, 0.f, 0.f};
#pragma unroll
        for (int set = 0; set < 2; ++set)
#pragma unroll
            for (int s = 0; s < 2; ++s) c[set][s] = zero4;

#pragma unroll
        for (int kk = 0; kk < 13; ++kk) {
            int koff = kk * 32 + quad * 8;
#pragma unroll
            for (int s = 0; s < 2; ++s) {
                bf16x8 bfr = *(const bf16x8*)(&h_lds[(s * 16 + lrow) * LDH + koff]);
                c[0][s] = __builtin_amdgcn_mfma_f32_16x16x32_bf16(afrag[0][kk], bfr, c[0][s], 0, 0, 0);
                c[1][s] = __builtin_amdgcn_mfma_f32_16x16x32_bf16(afrag[1][kk], bfr, c[1][s], 0, 0, 0);
            }
        }

        if (t0 + NT_FB > len) {
#pragma unroll
            for (int s = 0; s < 2; ++s) {
                int t = t0 + s * 16 + lrow;
                if (t >= len) {
#pragma unroll
                    for (int set = 0; set < 2; ++set) {
                        c[set][s][0] = -3.0e38f; c[set][s][1] = -3.0e38f;
                        c[set][s][2] = -3.0e38f; c[set][s][3] = -3.0e38f;
                    }
                }
            }
        }

        float hw0 = hw_lds[lrow], hw1 = hw_lds[16 + lrow];
        float cm = -3.0e38f;
#pragma unroll
        for (int set = 0; set < 2; ++set)
#pragma unroll
            for (int s = 0; s < 2; ++s)
#pragma unroll
                for (int r = 0; r < 4; ++r) cm = fmaxf(cm, c[set][s][r]);
        float mn = fmaxf(m_s, cm);
        float alpha = __expf(m_s - mn);
        m_s = mn;
#pragma unroll
        for (int set = 0; set < 2; ++set)
#pragma unroll
            for (int r = 0; r < 4; ++r) {
                float p0 = __expf(c[set][0][r] - mn);
                float p1 = __expf(c[set][1][r] - mn);
                l_s[set][r] = l_s[set][r] * alpha + (p0 + p1);
                a_s[set][r] = a_s[set][r] * alpha + (p0 * hw0 + p1 * hw1);
            }
    }

#pragma unroll
    for (int set = 0; set < 2; ++set)
#pragma unroll
        for (int r = 0; r < 4; ++r) {
            float m = m_s, l = l_s[set][r], a = a_s[set][r];
#pragma unroll
            for (int off = 1; off < 16; off <<= 1) {
                float mo = __shfl_xor(m, off, 64);
                float lo = __shfl_xor(l, off, 64);
                float ao = __shfl_xor(a, off, 64);
                float mx = fmaxf(m, mo);
                float f1 = __expf(m - mx), f2 = __expf(mo - mx);
                l = l * f1 + lo * f2;
                a = a * f1 + ao * f2;
                m = mx;
            }
            if (lrow == 0) {
                int v = vbase + wave * 32 + set * 16 + quad * 4 + r;
                out[(size_t)b * NV + v] = a / l + b0;
            }
        }
}

// ---------------------------------------------------------------------------
extern "C" void kernel_launch(void* const* d_in, const int* in_sizes, int n_in,
                              void* d_out, int out_size, void* d_ws, size_t ws_size,
                              hipStream_t stream) {
    const float* H    = (const float*)d_in[0];   // (B,T,D)
    const float* cu   = (const float*)d_in[1];   // (B,D)
    const float* Ca   = (const float*)d_in[2];   // (B,NA,D)
    const float* Cv   = (const float*)d_in[3];   // (NV,1,D)
    const float* W    = (const float*)d_in[4];   // (1,D)
    const float* bs   = (const float*)d_in[5];   // (1,)
    const int*   lens = (const int*)d_in[6];     // (B,)
    float* out = (float*)d_out;                  // f32: y_utts (B,NV) ++ y_acts (B,NV)

    float*  hw   = (float*)d_ws;                        // B*T f32 (256 KB)
    float*  q_ws = hw + (size_t)B_ * T_;                // B*D f32 (200 KB)
    float*  s2   = q_ws + (size_t)B_ * D_;              // B*NA f32 (64 KB)
    bf16_t* Hf   = (bf16_t*)(s2 + (size_t)B_ * NA);     // 4096 tiles x 13312 B (54.5 MB)

    size_t need = ((size_t)B_ * T_ + (size_t)B_ * D_ + (size_t)B_ * NA) * sizeof(float)
                + (size_t)4096 * TILE_BYTES;
    bool pre = (ws_size >= need);

    if (pre) {
        prep_kernel<<<dim3(1024 + B_ * NA / 4), dim3(256), 0, stream>>>(H, W, Ca, cu, hw, Hf, s2);
        qacts_kernel<<<dim3(B_), dim3(256), 0, stream>>>(s2, Ca, q_ws);
        attn_kernel<<<dim3(ATTN_BLOCKS), dim3(256), 0, stream>>>(Hf, Cv, hw, bs, lens, out);
        yacts_kernel<<<dim3(B_ * NV / 16), dim3(256), 0, stream>>>(q_ws, Cv, out);
    } else {
        prep_fb_kernel<<<dim3(B_ * T_ / 4 + B_ * NA / 4), dim3(256), 0, stream>>>(H, W, Ca, cu, hw, s2);
        qacts_kernel<<<dim3(B_), dim3(256), 0, stream>>>(s2, Ca, q_ws);
        main_fb_kernel<<<dim3(FB_MAIN_BLOCKS), dim3(256), 0, stream>>>(H, Cv, hw, bs, lens, out);
        yacts_kernel<<<dim3(B_ * NV / 16), dim3(256), 0, stream>>>(q_ws, Cv, out);
    }
}